// Round 12
// baseline (4409.674 us; speedup 1.0000x reference)
//
#include <hip/hip_runtime.h>
#include <float.h>
#include <math.h>

#define NB 4
#define NPTS 8192
#define NS 4096
#define MIDC 32
#define OUTC 64
#define CATC 67
#define BN_EPS 1e-5f
#define TOTAL_PTS (NB*NPTS)   // 32768
#define TOTAL_S (NB*NS)       // 16384

// Packed selection key: for non-negative doubles the IEEE754 bit pattern is
// order-isomorphic to the value. Truncate the low 13 mantissa bits (2^-39 rel
// noise vs ~1e-4 boundary gaps) and store a 13-bit id there: (dist,id) compare
// becomes one f64 compare, and min-update is a single fmin.

__device__ __forceinline__ double packkey(double d, int sp) {
    return __longlong_as_double((__double_as_longlong(d) & 0xFFFFFFFFFFFFE000ULL)
                                | (unsigned long long)sp);
}

// f64 max with a DPP-moved partner (VALU-speed cross-lane). Keys >= 0 so
// old=0 for masked rows is identity under fmax.
template<int CTRL, int RM>
__device__ __forceinline__ double dpp_fmax64(double v) {
    int lo = __builtin_amdgcn_update_dpp(0, __double2loint(v), CTRL, RM, 0xF, false);
    int hi = __builtin_amdgcn_update_dpp(0, __double2hiint(v), CTRL, RM, 0xF, false);
    return fmax(v, __hiloint2double(hi, lo));
}

// ---------------- init: zero group-stats accumulators + xin moments ----------------
__global__ void k_init(float* __restrict__ stats, double* __restrict__ mom) {
    int tid = threadIdx.x;
    if (tid < 128) stats[64 + tid] = 0.f;     // group sum/sq accumulators
    if (tid < 9) mom[tid] = 0.0;              // xin moment accumulators
}

// ---------------- xin moments: E[x], E[x x^T] (f64) ----------------
__global__ void __launch_bounds__(256) k_mom(const float* __restrict__ xin, double* __restrict__ mom) {
    int t = blockIdx.x * 256 + threadIdx.x;   // 8192 threads x 4 pts
    double sx = 0, sy = 0, sz = 0, sxx = 0, sxy = 0, sxz = 0, syy = 0, syz = 0, szz = 0;
#pragma unroll
    for (int j = 0; j < 4; j++) {
        int p = t * 4 + j;
        double x = (double)xin[p * 3], y = (double)xin[p * 3 + 1], z = (double)xin[p * 3 + 2];
        sx += x; sy += y; sz += z;
        sxx = fma(x, x, sxx); sxy = fma(x, y, sxy); sxz = fma(x, z, sxz);
        syy = fma(y, y, syy); syz = fma(y, z, syz); szz = fma(z, z, szz);
    }
#pragma unroll
    for (int off = 32; off; off >>= 1) {
        sx += __shfl_down(sx, off); sy += __shfl_down(sy, off); sz += __shfl_down(sz, off);
        sxx += __shfl_down(sxx, off); sxy += __shfl_down(sxy, off); sxz += __shfl_down(sxz, off);
        syy += __shfl_down(syy, off); syz += __shfl_down(syz, off); szz += __shfl_down(szz, off);
    }
    if ((threadIdx.x & 63) == 0) {
        atomicAdd(&mom[0], sx); atomicAdd(&mom[1], sy); atomicAdd(&mom[2], sz);
        atomicAdd(&mom[3], sxx); atomicAdd(&mom[4], sxy); atomicAdd(&mom[5], sxz);
        atomicAdd(&mom[6], syy); atomicAdd(&mom[7], syz); atomicAdd(&mom[8], szz);
    }
}

// ---------------- BN1 stats analytically: mu = W1.m + b1; var = W1^T C W1 ----------------
__global__ void k_bn1stats(const double* __restrict__ mom, const float* __restrict__ W1,
                           const float* __restrict__ b1, float* __restrict__ stats) {
    int c = threadIdx.x;  // 32
    double n = (double)TOTAL_PTS;
    double mx = mom[0] / n, my = mom[1] / n, mz = mom[2] / n;
    double Cxx = mom[3] / n - mx * mx, Cxy = mom[4] / n - mx * my, Cxz = mom[5] / n - mx * mz;
    double Cyy = mom[6] / n - my * my, Cyz = mom[7] / n - my * mz, Czz = mom[8] / n - mz * mz;
    double wx = (double)W1[c * 3], wy = (double)W1[c * 3 + 1], wz = (double)W1[c * 3 + 2];
    double mu = wx * mx + wy * my + wz * mz + (double)b1[c];
    double var = wx * wx * Cxx + wy * wy * Cyy + wz * wz * Czz
               + 2.0 * (wx * wy * Cxy + wx * wz * Cxz + wy * wz * Cyz);
    stats[c] = (float)mu;
    stats[32 + c] = rsqrtf(fmaxf((float)var, 0.f) + BN_EPS);
}

// ---------------- fused conv1+BN1+ReLU+conv2: xin -> feat ----------------
__global__ void __launch_bounds__(256) k_featx(const float* __restrict__ xin, const float* __restrict__ stats,
                                               const float* __restrict__ W1, const float* __restrict__ b1,
                                               const float* __restrict__ g1, const float* __restrict__ be1,
                                               const float* __restrict__ W2, const float* __restrict__ b2,
                                               float* __restrict__ feat) {
    __shared__ float W2s[OUTC * MIDC];
    __shared__ float w1s[MIDC * 3], p1[MIDC], p2[MIDC];   // BN folded per channel
    int tid = threadIdx.x;
    for (int i = tid; i < OUTC * MIDC; i += 256) W2s[i] = W2[i];
    if (tid < MIDC * 3) w1s[tid] = W1[tid];
    if (tid < MIDC) { p1[tid] = stats[32 + tid] * g1[tid]; p2[tid] = be1[tid] - stats[tid] * stats[32 + tid] * g1[tid]; }
    __syncthreads();
    int p = blockIdx.x * blockDim.x + tid;
    float x = xin[p * 3], y = xin[p * 3 + 1], z = xin[p * 3 + 2];
    float h[MIDC];
#pragma unroll
    for (int c = 0; c < MIDC; c++) {
        // same association as original k_first: fmaf chain
        float v = fmaf(w1s[c * 3 + 2], z, fmaf(w1s[c * 3 + 1], y, fmaf(w1s[c * 3], x, b1[c])));
        h[c] = fmaxf(fmaf(v, p1[c], p2[c]), 0.f);
    }
#pragma unroll 4
    for (int o = 0; o < OUTC; o++) {
        float a = b2[o];
#pragma unroll
        for (int c = 0; c < MIDC; c++) a = fmaf(W2s[o * MIDC + c], h[c], a);
        feat[p * OUTC + o] = a;
    }
}

// ---------------- farthest point sampling: Morton-clustered lazy-exact (r11 structure) ----------------
__device__ __forceinline__ unsigned int mpart(unsigned int x) {
    x &= 1023u;
    x = (x | (x << 16)) & 0x030000FFu;
    x = (x | (x << 8))  & 0x0300F00Fu;
    x = (x | (x << 4))  & 0x030C30C3u;
    x = (x | (x << 2))  & 0x09249249u;
    return x;
}

__global__ void __launch_bounds__(1024, 4) k_fps(const float* __restrict__ xin, int* __restrict__ fidx) {
    const int b = blockIdx.x;
    const int tid = threadIdx.x;
    const int lane = tid & 63, w = tid >> 6;  // 16 waves
    const float* xb = xin + (size_t)b * NPTS * 3;
    __shared__ union UU {
        struct SS {
            float4 spts[NPTS];       // 131072 B, swizzled, .w = orig idx bits
            double swd[2][16];       // 256 B
            float  bbx[16][6];       // 384 B
        } s;
        unsigned long long karr[NPTS];  // 65536 B, phases 0-2 only (overlaps spts)
    } u;

    // ---- phase 0: batch bbox ----
    float mnx = FLT_MAX, mny = FLT_MAX, mnz = FLT_MAX;
    float mxx = -FLT_MAX, mxy = -FLT_MAX, mxz = -FLT_MAX;
    for (int j = 0; j < 8; j++) {
        int p = tid + (j << 10);
        float x = xb[p * 3], y = xb[p * 3 + 1], z = xb[p * 3 + 2];
        mnx = fminf(mnx, x); mny = fminf(mny, y); mnz = fminf(mnz, z);
        mxx = fmaxf(mxx, x); mxy = fmaxf(mxy, y); mxz = fmaxf(mxz, z);
    }
#pragma unroll
    for (int off = 32; off; off >>= 1) {
        mnx = fminf(mnx, __shfl_xor(mnx, off)); mny = fminf(mny, __shfl_xor(mny, off));
        mnz = fminf(mnz, __shfl_xor(mnz, off));
        mxx = fmaxf(mxx, __shfl_xor(mxx, off)); mxy = fmaxf(mxy, __shfl_xor(mxy, off));
        mxz = fmaxf(mxz, __shfl_xor(mxz, off));
    }
    if (lane == 0) {
        u.s.bbx[w][0] = mnx; u.s.bbx[w][1] = mny; u.s.bbx[w][2] = mnz;
        u.s.bbx[w][3] = mxx; u.s.bbx[w][4] = mxy; u.s.bbx[w][5] = mxz;
    }
    __syncthreads();
#pragma unroll
    for (int i = 0; i < 16; i++) {
        mnx = fminf(mnx, u.s.bbx[i][0]); mny = fminf(mny, u.s.bbx[i][1]);
        mnz = fminf(mnz, u.s.bbx[i][2]);
        mxx = fmaxf(mxx, u.s.bbx[i][3]); mxy = fmaxf(mxy, u.s.bbx[i][4]);
        mxz = fmaxf(mxz, u.s.bbx[i][5]);
    }
    float scx = 1023.0f / fmaxf(mxx - mnx, 1e-20f);
    float scy = 1023.0f / fmaxf(mxy - mny, 1e-20f);
    float scz = 1023.0f / fmaxf(mxz - mnz, 1e-20f);
    __syncthreads();

    // ---- phase 1: Morton keys + bitonic sort ----
    for (int j = 0; j < 8; j++) {
        int p = tid + (j << 10);
        float x = xb[p * 3], y = xb[p * 3 + 1], z = xb[p * 3 + 2];
        unsigned int ix = (unsigned int)min(1023, max(0, (int)((x - mnx) * scx)));
        unsigned int iy = (unsigned int)min(1023, max(0, (int)((y - mny) * scy)));
        unsigned int iz = (unsigned int)min(1023, max(0, (int)((z - mnz) * scz)));
        unsigned long long code = (unsigned long long)((mpart(ix) << 2) | (mpart(iy) << 1) | mpart(iz));
        u.karr[p] = (code << 13) | (unsigned long long)p;
    }
    __syncthreads();
    for (int k = 2; k <= NPTS; k <<= 1) {
        for (int jj = k >> 1; jj > 0; jj >>= 1) {
            for (int pos = tid; pos < NPTS; pos += 1024) {
                int l2 = pos ^ jj;
                if (l2 > pos) {
                    unsigned long long a = u.karr[pos], c = u.karr[l2];
                    bool up = ((pos & k) == 0);
                    if ((up && a > c) || (!up && a < c)) { u.karr[pos] = c; u.karr[l2] = a; }
                }
            }
            __syncthreads();
        }
    }

    // ---- phase 2: gather sorted points into swizzled LDS, per-thread box ----
    unsigned long long kk[8];
#pragma unroll
    for (int j = 0; j < 8; j++) kk[j] = u.karr[tid * 8 + j];
    __syncthreads();  // all karr reads done; spts writes may clobber it
    float blox = FLT_MAX, bloy = FLT_MAX, bloz = FLT_MAX;
    float bhix = -FLT_MAX, bhiy = -FLT_MAX, bhiz = -FLT_MAX;
    double dk[8];
#pragma unroll
    for (int j = 0; j < 8; j++) {
        int oi = (int)(kk[j] & 0x1FFFULL);
        float x = xb[oi * 3], y = xb[oi * 3 + 1], z = xb[oi * 3 + 2];
        int sp = tid * 8 + j;
        int slot = (sp >> 3) | ((sp & 7) << 10);
        u.s.spts[slot] = make_float4(x, y, z, __int_as_float(oi));
        blox = fminf(blox, x); bloy = fminf(bloy, y); bloz = fminf(bloz, z);
        bhix = fmaxf(bhix, x); bhiy = fmaxf(bhiy, y); bhiz = fmaxf(bhiz, z);
        dk[j] = packkey(1e10, sp);
    }
    if (tid == 0) fidx[b * NS] = 0;
    __syncthreads();

    // ---- phase 3: main loop ----
    float cxf = xb[0], cyf = xb[1], czf = xb[2];
    double cx = (double)cxf, cy = (double)cyf, cz = (double)czf;
    double tmax = packkey(1e10, tid * 8 + 7);
    double wm = 0.0;   // valid after first reduce (t=1 always updates)
    for (int t = 1; t < NS; t++) {
        float exf = fmaxf(fmaxf(blox - cxf, cxf - bhix), 0.f);
        float eyf = fmaxf(fmaxf(bloy - cyf, cyf - bhiy), 0.f);
        float ezf = fmaxf(fmaxf(bloz - czf, czf - bhiz), 0.f);
        float dmsqf = fmaf(exf, exf, fmaf(eyf, eyf, ezf * ezf));
        double tupper = __longlong_as_double(__double_as_longlong(tmax) | 0x1FFFULL);
        bool doupd = !((double)dmsqf * 0.99999 > tupper);
        if (__any(doupd)) {
            if (doupd) {
                double t0 = 0.0, t1 = 0.0;
#pragma unroll
                for (int j = 0; j < 8; j += 2) {
                    float4 v0 = u.s.spts[tid | (j << 10)];
                    float4 v1 = u.s.spts[tid | ((j + 1) << 10)];
                    double dx0 = (double)v0.x - cx, dy0 = (double)v0.y - cy, dz0 = (double)v0.z - cz;
                    double d0 = fma(dx0, dx0, fma(dy0, dy0, dz0 * dz0));
                    double nk0 = fmin(dk[j], packkey(d0, tid * 8 + j));
                    dk[j] = nk0; t0 = fmax(t0, nk0);
                    double dx1 = (double)v1.x - cx, dy1 = (double)v1.y - cy, dz1 = (double)v1.z - cz;
                    double d1 = fma(dx1, dx1, fma(dy1, dy1, dz1 * dz1));
                    double nk1 = fmin(dk[j + 1], packkey(d1, tid * 8 + j + 1));
                    dk[j + 1] = nk1; t1 = fmax(t1, nk1);
                }
                tmax = fmax(t0, t1);
            }
            double v = tmax;
            v = dpp_fmax64<0x121, 0xF>(v);
            v = dpp_fmax64<0x122, 0xF>(v);
            v = dpp_fmax64<0x124, 0xF>(v);
            v = dpp_fmax64<0x128, 0xF>(v);
            v = dpp_fmax64<0x142, 0xa>(v);
            v = dpp_fmax64<0x143, 0x8>(v);
            int wlo = __builtin_amdgcn_readlane(__double2loint(v), 63);
            int whi = __builtin_amdgcn_readlane(__double2hiint(v), 63);
            wm = __hiloint2double(whi, wlo);
        }
        if (lane == 0) u.s.swd[t & 1][w] = wm;
        __syncthreads();
        double gv = u.s.swd[t & 1][lane & 15];
        gv = dpp_fmax64<0x121, 0xF>(gv);
        gv = dpp_fmax64<0x122, 0xF>(gv);
        gv = dpp_fmax64<0x124, 0xF>(gv);
        gv = dpp_fmax64<0x128, 0xF>(gv);
        int sp = (int)((unsigned int)__double_as_longlong(gv) & 0x1FFFu);
        float4 cw = u.s.spts[(sp >> 3) | ((sp & 7) << 10)];  // same addr: broadcast
        cxf = cw.x; cyf = cw.y; czf = cw.z;
        cx = (double)cxf; cy = (double)cyf; cz = (double)czf;
        if (tid == 0) fidx[b * NS + t] = __float_as_int(cw.w);
    }
}

// ---------------- brute-force kNN top-16: f32 prefilter, f64-exact inserts ----------------
// Skip rule: true insert means d64 < kd15. |d32-d64| <= 2.4e-7 rel, kd15f is a
// rounded-up f32 of kd15 times (1+1e-5) -> every true insert satisfies
// d32 <= kd15f. Selection provably identical to the all-f64 version.
#define KT2 1024
__global__ void __launch_bounds__(256) k_knn(const float* __restrict__ xin, const int* __restrict__ fidx,
                                             int* __restrict__ knn) {
    __shared__ float sxf[KT2], syf[KT2], szf[KT2];      // 12 KB
    __shared__ double mk[4][16][64];                     // 32 KB: [part][rank][query]
    int tid = threadIdx.x;
    int part = tid >> 6;
    int ql = tid & 63;
    int gq = blockIdx.x * 64 + ql;
    int b = gq >> 12;
    const float* xb = xin + (size_t)b * NPTS * 3;
    int qi = fidx[gq];
    float qxf = xb[qi * 3], qyf = xb[qi * 3 + 1], qzf = xb[qi * 3 + 2];
    double qx = (double)qxf, qy = (double)qyf, qz = (double)qzf;
    double kd0 = DBL_MAX, kd1 = DBL_MAX, kd2 = DBL_MAX, kd3 = DBL_MAX,
           kd4 = DBL_MAX, kd5 = DBL_MAX, kd6 = DBL_MAX, kd7 = DBL_MAX,
           kd8 = DBL_MAX, kd9 = DBL_MAX, kd10 = DBL_MAX, kd11 = DBL_MAX,
           kd12 = DBL_MAX, kd13 = DBL_MAX, kd14 = DBL_MAX, kd15 = DBL_MAX;
    float kd15f = FLT_MAX;
    for (int tile = 0; tile < NPTS / KT2; tile++) {
        for (int m = tid; m < KT2; m += 256) {
            int gj = tile * KT2 + m;
            sxf[m] = xb[gj * 3]; syf[m] = xb[gj * 3 + 1]; szf[m] = xb[gj * 3 + 2];
        }
        __syncthreads();
        int base = part * (KT2 / 4);
        for (int m = 0; m < KT2 / 4; m++) {
            int li = base + m;
            float fdx = qxf - sxf[li], fdy = qyf - syf[li], fdz = qzf - szf[li];
            float d32 = fmaf(fdx, fdx, fmaf(fdy, fdy, fdz * fdz));
            if (d32 <= kd15f) {
                double dx = qx - (double)sxf[li], dy = qy - (double)syf[li], dz = qz - (double)szf[li];
                double d = fma(dx, dx, fma(dy, dy, dz * dz));
                double key = __longlong_as_double(
                    (__double_as_longlong(d) & 0xFFFFFFFFFFFFE000ULL)
                    | (unsigned long long)(tile * KT2 + li));
                if (key < kd15) {
                    kd15 = fmax(kd14, fmin(kd15, key)); kd14 = fmax(kd13, fmin(kd14, key));
                    kd13 = fmax(kd12, fmin(kd13, key)); kd12 = fmax(kd11, fmin(kd12, key));
                    kd11 = fmax(kd10, fmin(kd11, key)); kd10 = fmax(kd9,  fmin(kd10, key));
                    kd9  = fmax(kd8,  fmin(kd9,  key)); kd8  = fmax(kd7,  fmin(kd8,  key));
                    kd7  = fmax(kd6,  fmin(kd7,  key)); kd6  = fmax(kd5,  fmin(kd6,  key));
                    kd5  = fmax(kd4,  fmin(kd5,  key)); kd4  = fmax(kd3,  fmin(kd4,  key));
                    kd3  = fmax(kd2,  fmin(kd3,  key)); kd2  = fmax(kd1,  fmin(kd2,  key));
                    kd1  = fmax(kd0,  fmin(kd1,  key)); kd0  = fmin(kd0,  key);
                    kd15f = (kd15 >= DBL_MAX) ? FLT_MAX
                          : __double2float_ru(kd15) * (1.0f + 1e-5f);
                }
            }
        }
        __syncthreads();
    }
    mk[part][0][ql] = kd0;  mk[part][1][ql] = kd1;  mk[part][2][ql] = kd2;  mk[part][3][ql] = kd3;
    mk[part][4][ql] = kd4;  mk[part][5][ql] = kd5;  mk[part][6][ql] = kd6;  mk[part][7][ql] = kd7;
    mk[part][8][ql] = kd8;  mk[part][9][ql] = kd9;  mk[part][10][ql] = kd10; mk[part][11][ql] = kd11;
    mk[part][12][ql] = kd12; mk[part][13][ql] = kd13; mk[part][14][ql] = kd14; mk[part][15][ql] = kd15;
    __syncthreads();
    if (tid < 64) {
        int i0 = 0, i1 = 0, i2 = 0, i3 = 0;
        double h0 = mk[0][0][tid], h1 = mk[1][0][tid], h2 = mk[2][0][tid], h3 = mk[3][0][tid];
        int* outp = knn + (size_t)(blockIdx.x * 64 + tid) * 16;
#pragma unroll
        for (int k = 0; k < 16; k++) {
            double mm = fmin(fmin(h0, h1), fmin(h2, h3));
            outp[k] = (int)(__double_as_longlong(mm) & 0x1FFFULL);
            if (mm == h0)      { i0++; h0 = (i0 < 16) ? mk[0][i0][tid] : DBL_MAX; }
            else if (mm == h1) { i1++; h1 = (i1 < 16) ? mk[1][i1][tid] : DBL_MAX; }
            else if (mm == h2) { i2++; h2 = (i2 < 16) ? mk[2][i2][tid] : DBL_MAX; }
            else               { i3++; h3 = (i3 < 16) ? mk[3][i3][tid] : DBL_MAX; }
        }
    }
}

// ---------------- gather + maxpool(67) + conv3 (wave per point, no per-iter barriers) ----------------
// x67[w] is produced and consumed by wave w only -> wave-synchronous LDS,
// ordering guaranteed by lgkmcnt; the old per-iteration __syncthreads were
// pure overhead (32 barriers/block removed).
__global__ void __launch_bounds__(256) k_group(const float* __restrict__ xin, const float* __restrict__ feat,
                                               const int* __restrict__ fidx, const int* __restrict__ knn,
                                               const float* __restrict__ W3, const float* __restrict__ b3,
                                               float* __restrict__ y3, float* __restrict__ stats) {
    __shared__ float W3s[OUTC * CATC];
    __shared__ float x67[4][68];
    __shared__ float lsum[64], lsq[64];
    int tid = threadIdx.x, w = tid >> 6, lane = tid & 63;
    for (int i = tid; i < OUTC * CATC; i += 256) W3s[i] = W3[i];
    if (tid < 64) { lsum[tid] = 0.f; lsq[tid] = 0.f; }
    __syncthreads();
    float psum = 0.f, psq = 0.f;
    int p0 = blockIdx.x * 64 + w * 16;
    for (int it = 0; it < 16; it++) {
        int p = p0 + it;
        int b = p >> 12;
        int myidx = knn[p * 16 + (lane & 15)];
        int nbk[16];
#pragma unroll
        for (int k = 0; k < 16; k++) nbk[k] = __shfl(myidx, k);
        float m = -FLT_MAX;
#pragma unroll
        for (int k = 0; k < 16; k++) m = fmaxf(m, feat[(size_t)(b * NPTS + nbk[k]) * OUTC + lane]);
        x67[w][3 + lane] = m;
        if (lane < 3) {
            int ci = fidx[p];
            float cc = xin[(size_t)(b * NPTS + ci) * 3 + lane];
            float mg = -FLT_MAX;
#pragma unroll
            for (int k = 0; k < 16; k++) mg = fmaxf(mg, xin[(size_t)(b * NPTS + nbk[k]) * 3 + lane] - cc);
            x67[w][lane] = mg;
        }
        float acc = b3[lane];
#pragma unroll
        for (int c = 0; c < CATC; c++) acc = fmaf(W3s[lane * CATC + c], x67[w][c], acc);
        y3[(size_t)p * OUTC + lane] = acc;
        psum += acc; psq = fmaf(acc, acc, psq);
    }
    atomicAdd(&lsum[lane], psum);
    atomicAdd(&lsq[lane], psq);
    __syncthreads();
    if (tid < 64) { atomicAdd(&stats[64 + tid], lsum[tid]); atomicAdd(&stats[128 + tid], lsq[tid]); }
}

// ---------------- BN2 finalize ----------------
__global__ void k_stats2(float* __restrict__ stats) {
    int c = threadIdx.x;  // 64
    float m = stats[64 + c] / (float)TOTAL_S;
    float var = stats[128 + c] / (float)TOTAL_S - m * m;
    stats[192 + c] = m;
    stats[256 + c] = rsqrtf(var + BN_EPS);
}

// ---------------- final conv with fused BN2+ReLU ----------------
__global__ void __launch_bounds__(256) k_last(const float* __restrict__ y3, const float* __restrict__ stats,
                                              const float* __restrict__ g2, const float* __restrict__ be2,
                                              const float* __restrict__ W4, const float* __restrict__ b4,
                                              float* __restrict__ out) {
    __shared__ float W4t[OUTC * OUTC];
    __shared__ float xs[4][64];
    int tid = threadIdx.x;
    for (int i = tid; i < OUTC * OUTC; i += 256) W4t[(i & 63) * 64 + (i >> 6)] = W4[i];
    int lp = tid >> 6, o = tid & 63;
    int p = blockIdx.x * 4 + lp;
    float v = y3[(size_t)p * OUTC + o];
    v = fmaf((v - stats[192 + o]) * stats[256 + o], g2[o], be2[o]);
    xs[lp][o] = fmaxf(v, 0.f);
    __syncthreads();
    const float* xp = xs[lp];
    float acc = b4[o];
#pragma unroll
    for (int c = 0; c < OUTC; c++) acc = fmaf(W4t[c * 64 + o], xp[c], acc);
    out[(size_t)p * OUTC + o] = acc;
}

extern "C" void kernel_launch(void* const* d_in, const int* in_sizes, int n_in,
                              void* d_out, int out_size, void* d_ws, size_t ws_size,
                              hipStream_t stream) {
    const float* xin = (const float*)d_in[0];
    const float* W1  = (const float*)d_in[1];
    const float* b1  = (const float*)d_in[2];
    const float* g1  = (const float*)d_in[3];
    const float* be1 = (const float*)d_in[4];
    const float* W2  = (const float*)d_in[5];
    const float* b2  = (const float*)d_in[6];
    const float* W3  = (const float*)d_in[7];
    const float* b3  = (const float*)d_in[8];
    const float* g2  = (const float*)d_in[9];
    const float* be2 = (const float*)d_in[10];
    const float* W4  = (const float*)d_in[11];
    const float* b4  = (const float*)d_in[12];
    float* out = (float*)d_out;

    float* ws = (float*)d_ws;
    float* feat = ws;                                       // 32768*64 = 2,097,152 f
    int*   fidx = (int*)(feat + (size_t)TOTAL_PTS * OUTC);  // 16384 i
    int*   knn  = fidx + TOTAL_S;                           // 262,144 i
    float* y3   = (float*)(knn + (size_t)TOTAL_S * 16);     // 1,048,576 f
    float* stats = y3 + (size_t)TOTAL_S * OUTC;             // 320 f
    double* mom = (double*)(stats + 320);                   // 9 d (8-aligned: all prior counts even)

    k_init<<<1, 256, 0, stream>>>(stats, mom);
    k_mom<<<32, 256, 0, stream>>>(xin, mom);
    k_bn1stats<<<1, 32, 0, stream>>>(mom, W1, b1, stats);
    k_featx<<<TOTAL_PTS / 256, 256, 0, stream>>>(xin, stats, W1, b1, g1, be1, W2, b2, feat);
    k_fps<<<NB, 1024, 0, stream>>>(xin, fidx);
    k_knn<<<TOTAL_S / 64, 256, 0, stream>>>(xin, fidx, knn);
    k_group<<<TOTAL_S / 64, 256, 0, stream>>>(xin, feat, fidx, knn, W3, b3, y3, stats);
    k_stats2<<<1, 64, 0, stream>>>(stats);
    k_last<<<TOTAL_S / 4, 256, 0, stream>>>(y3, stats, g2, be2, W4, b4, out);
}

// Round 13
// 4401.146 us; speedup vs baseline: 1.0019x; 1.0019x over previous
//
#include <hip/hip_runtime.h>
#include <float.h>
#include <math.h>

#define NB 4
#define NPTS 8192
#define NS 4096
#define MIDC 32
#define OUTC 64
#define CATC 67
#define BN_EPS 1e-5f
#define TOTAL_PTS (NB*NPTS)   // 32768
#define TOTAL_S (NB*NS)       // 16384

// Packed selection key: for non-negative doubles the IEEE754 bit pattern is
// order-isomorphic to the value. Truncate the low 13 mantissa bits (2^-39 rel
// noise vs ~1e-4 boundary gaps) and store a 13-bit id there: (dist,id) compare
// becomes one f64 compare, and min-update is a single fmin.

__device__ __forceinline__ double packkey(double d, int sp) {
    return __longlong_as_double((__double_as_longlong(d) & 0xFFFFFFFFFFFFE000ULL)
                                | (unsigned long long)sp);
}

// f64 max with a DPP-moved partner (VALU-speed cross-lane). Keys >= 0 so
// old=0 for masked rows is identity under fmax.
template<int CTRL, int RM>
__device__ __forceinline__ double dpp_fmax64(double v) {
    int lo = __builtin_amdgcn_update_dpp(0, __double2loint(v), CTRL, RM, 0xF, false);
    int hi = __builtin_amdgcn_update_dpp(0, __double2hiint(v), CTRL, RM, 0xF, false);
    return fmax(v, __hiloint2double(hi, lo));
}

// ---------------- init: zero group-stats accumulators + xin moments ----------------
__global__ void k_init(float* __restrict__ stats, double* __restrict__ mom) {
    int tid = threadIdx.x;
    if (tid < 128) stats[64 + tid] = 0.f;     // group sum/sq accumulators
    if (tid < 9) mom[tid] = 0.0;              // xin moment accumulators
}

// ---------------- xin moments: E[x], E[x x^T] (f64) ----------------
__global__ void __launch_bounds__(256) k_mom(const float* __restrict__ xin, double* __restrict__ mom) {
    int t = blockIdx.x * 256 + threadIdx.x;   // 8192 threads x 4 pts
    double sx = 0, sy = 0, sz = 0, sxx = 0, sxy = 0, sxz = 0, syy = 0, syz = 0, szz = 0;
#pragma unroll
    for (int j = 0; j < 4; j++) {
        int p = t * 4 + j;
        double x = (double)xin[p * 3], y = (double)xin[p * 3 + 1], z = (double)xin[p * 3 + 2];
        sx += x; sy += y; sz += z;
        sxx = fma(x, x, sxx); sxy = fma(x, y, sxy); sxz = fma(x, z, sxz);
        syy = fma(y, y, syy); syz = fma(y, z, syz); szz = fma(z, z, szz);
    }
#pragma unroll
    for (int off = 32; off; off >>= 1) {
        sx += __shfl_down(sx, off); sy += __shfl_down(sy, off); sz += __shfl_down(sz, off);
        sxx += __shfl_down(sxx, off); sxy += __shfl_down(sxy, off); sxz += __shfl_down(sxz, off);
        syy += __shfl_down(syy, off); syz += __shfl_down(syz, off); szz += __shfl_down(szz, off);
    }
    if ((threadIdx.x & 63) == 0) {
        atomicAdd(&mom[0], sx); atomicAdd(&mom[1], sy); atomicAdd(&mom[2], sz);
        atomicAdd(&mom[3], sxx); atomicAdd(&mom[4], sxy); atomicAdd(&mom[5], sxz);
        atomicAdd(&mom[6], syy); atomicAdd(&mom[7], syz); atomicAdd(&mom[8], szz);
    }
}

// ---------------- BN1 stats analytically: mu = W1.m + b1; var = W1^T C W1 ----------------
__global__ void k_bn1stats(const double* __restrict__ mom, const float* __restrict__ W1,
                           const float* __restrict__ b1, float* __restrict__ stats) {
    int c = threadIdx.x;  // 32
    double n = (double)TOTAL_PTS;
    double mx = mom[0] / n, my = mom[1] / n, mz = mom[2] / n;
    double Cxx = mom[3] / n - mx * mx, Cxy = mom[4] / n - mx * my, Cxz = mom[5] / n - mx * mz;
    double Cyy = mom[6] / n - my * my, Cyz = mom[7] / n - my * mz, Czz = mom[8] / n - mz * mz;
    double wx = (double)W1[c * 3], wy = (double)W1[c * 3 + 1], wz = (double)W1[c * 3 + 2];
    double mu = wx * mx + wy * my + wz * mz + (double)b1[c];
    double var = wx * wx * Cxx + wy * wy * Cyy + wz * wz * Czz
               + 2.0 * (wx * wy * Cxy + wx * wz * Cxz + wy * wz * Cyz);
    stats[c] = (float)mu;
    stats[32 + c] = rsqrtf(fmaxf((float)var, 0.f) + BN_EPS);
}

// ---------------- fused conv1+BN1+ReLU+conv2: xin -> feat ----------------
__global__ void __launch_bounds__(256) k_featx(const float* __restrict__ xin, const float* __restrict__ stats,
                                               const float* __restrict__ W1, const float* __restrict__ b1,
                                               const float* __restrict__ g1, const float* __restrict__ be1,
                                               const float* __restrict__ W2, const float* __restrict__ b2,
                                               float* __restrict__ feat) {
    __shared__ float W2s[OUTC * MIDC];
    __shared__ float w1s[MIDC * 3], b1s[MIDC], p1[MIDC], p2[MIDC];   // BN folded per channel
    int tid = threadIdx.x;
    for (int i = tid; i < OUTC * MIDC; i += 256) W2s[i] = W2[i];
    if (tid < MIDC * 3) w1s[tid] = W1[tid];
    if (tid < MIDC) {
        b1s[tid] = b1[tid];
        p1[tid] = stats[32 + tid] * g1[tid];
        p2[tid] = be1[tid] - stats[tid] * stats[32 + tid] * g1[tid];
    }
    __syncthreads();
    int p = blockIdx.x * blockDim.x + tid;
    float x = xin[p * 3], y = xin[p * 3 + 1], z = xin[p * 3 + 2];
    float h[MIDC];
#pragma unroll
    for (int c = 0; c < MIDC; c++) {
        // same association as original k_first: fmaf chain
        float v = fmaf(w1s[c * 3 + 2], z, fmaf(w1s[c * 3 + 1], y, fmaf(w1s[c * 3], x, b1s[c])));
        h[c] = fmaxf(fmaf(v, p1[c], p2[c]), 0.f);
    }
#pragma unroll 4
    for (int o = 0; o < OUTC; o++) {
        float a = b2[o];
#pragma unroll
        for (int c = 0; c < MIDC; c++) a = fmaf(W2s[o * MIDC + c], h[c], a);
        feat[p * OUTC + o] = a;
    }
}

// ---------------- farthest point sampling: Morton-clustered lazy-exact (r11 structure) ----------------
__device__ __forceinline__ unsigned int mpart(unsigned int x) {
    x &= 1023u;
    x = (x | (x << 16)) & 0x030000FFu;
    x = (x | (x << 8))  & 0x0300F00Fu;
    x = (x | (x << 4))  & 0x030C30C3u;
    x = (x | (x << 2))  & 0x09249249u;
    return x;
}

__global__ void __launch_bounds__(1024, 4) k_fps(const float* __restrict__ xin, int* __restrict__ fidx) {
    const int b = blockIdx.x;
    const int tid = threadIdx.x;
    const int lane = tid & 63, w = tid >> 6;  // 16 waves
    const float* xb = xin + (size_t)b * NPTS * 3;
    __shared__ union UU {
        struct SS {
            float4 spts[NPTS];       // 131072 B, swizzled, .w = orig idx bits
            double swd[2][16];       // 256 B
            float  bbx[16][6];       // 384 B
        } s;
        unsigned long long karr[NPTS];  // 65536 B, phases 0-2 only (overlaps spts)
    } u;

    // ---- phase 0: batch bbox ----
    float mnx = FLT_MAX, mny = FLT_MAX, mnz = FLT_MAX;
    float mxx = -FLT_MAX, mxy = -FLT_MAX, mxz = -FLT_MAX;
    for (int j = 0; j < 8; j++) {
        int p = tid + (j << 10);
        float x = xb[p * 3], y = xb[p * 3 + 1], z = xb[p * 3 + 2];
        mnx = fminf(mnx, x); mny = fminf(mny, y); mnz = fminf(mnz, z);
        mxx = fmaxf(mxx, x); mxy = fmaxf(mxy, y); mxz = fmaxf(mxz, z);
    }
#pragma unroll
    for (int off = 32; off; off >>= 1) {
        mnx = fminf(mnx, __shfl_xor(mnx, off)); mny = fminf(mny, __shfl_xor(mny, off));
        mnz = fminf(mnz, __shfl_xor(mnz, off));
        mxx = fmaxf(mxx, __shfl_xor(mxx, off)); mxy = fmaxf(mxy, __shfl_xor(mxy, off));
        mxz = fmaxf(mxz, __shfl_xor(mxz, off));
    }
    if (lane == 0) {
        u.s.bbx[w][0] = mnx; u.s.bbx[w][1] = mny; u.s.bbx[w][2] = mnz;
        u.s.bbx[w][3] = mxx; u.s.bbx[w][4] = mxy; u.s.bbx[w][5] = mxz;
    }
    __syncthreads();
#pragma unroll
    for (int i = 0; i < 16; i++) {
        mnx = fminf(mnx, u.s.bbx[i][0]); mny = fminf(mny, u.s.bbx[i][1]);
        mnz = fminf(mnz, u.s.bbx[i][2]);
        mxx = fmaxf(mxx, u.s.bbx[i][3]); mxy = fmaxf(mxy, u.s.bbx[i][4]);
        mxz = fmaxf(mxz, u.s.bbx[i][5]);
    }
    float scx = 1023.0f / fmaxf(mxx - mnx, 1e-20f);
    float scy = 1023.0f / fmaxf(mxy - mny, 1e-20f);
    float scz = 1023.0f / fmaxf(mxz - mnz, 1e-20f);
    __syncthreads();

    // ---- phase 1: Morton keys + bitonic sort ----
    for (int j = 0; j < 8; j++) {
        int p = tid + (j << 10);
        float x = xb[p * 3], y = xb[p * 3 + 1], z = xb[p * 3 + 2];
        unsigned int ix = (unsigned int)min(1023, max(0, (int)((x - mnx) * scx)));
        unsigned int iy = (unsigned int)min(1023, max(0, (int)((y - mny) * scy)));
        unsigned int iz = (unsigned int)min(1023, max(0, (int)((z - mnz) * scz)));
        unsigned long long code = (unsigned long long)((mpart(ix) << 2) | (mpart(iy) << 1) | mpart(iz));
        u.karr[p] = (code << 13) | (unsigned long long)p;
    }
    __syncthreads();
    for (int k = 2; k <= NPTS; k <<= 1) {
        for (int jj = k >> 1; jj > 0; jj >>= 1) {
            for (int pos = tid; pos < NPTS; pos += 1024) {
                int l2 = pos ^ jj;
                if (l2 > pos) {
                    unsigned long long a = u.karr[pos], c = u.karr[l2];
                    bool up = ((pos & k) == 0);
                    if ((up && a > c) || (!up && a < c)) { u.karr[pos] = c; u.karr[l2] = a; }
                }
            }
            __syncthreads();
        }
    }

    // ---- phase 2: gather sorted points into swizzled LDS, per-thread box ----
    unsigned long long kk[8];
#pragma unroll
    for (int j = 0; j < 8; j++) kk[j] = u.karr[tid * 8 + j];
    __syncthreads();  // all karr reads done; spts writes may clobber it
    float blox = FLT_MAX, bloy = FLT_MAX, bloz = FLT_MAX;
    float bhix = -FLT_MAX, bhiy = -FLT_MAX, bhiz = -FLT_MAX;
    double dk[8];
#pragma unroll
    for (int j = 0; j < 8; j++) {
        int oi = (int)(kk[j] & 0x1FFFULL);
        float x = xb[oi * 3], y = xb[oi * 3 + 1], z = xb[oi * 3 + 2];
        int sp = tid * 8 + j;
        int slot = (sp >> 3) | ((sp & 7) << 10);
        u.s.spts[slot] = make_float4(x, y, z, __int_as_float(oi));
        blox = fminf(blox, x); bloy = fminf(bloy, y); bloz = fminf(bloz, z);
        bhix = fmaxf(bhix, x); bhiy = fmaxf(bhiy, y); bhiz = fmaxf(bhiz, z);
        dk[j] = packkey(1e10, sp);
    }
    if (tid == 0) fidx[b * NS] = 0;
    __syncthreads();

    // ---- phase 3: main loop ----
    float cxf = xb[0], cyf = xb[1], czf = xb[2];
    double cx = (double)cxf, cy = (double)cyf, cz = (double)czf;
    double tmax = packkey(1e10, tid * 8 + 7);
    double wm = 0.0;   // valid after first reduce (t=1 always updates)
    for (int t = 1; t < NS; t++) {
        float exf = fmaxf(fmaxf(blox - cxf, cxf - bhix), 0.f);
        float eyf = fmaxf(fmaxf(bloy - cyf, cyf - bhiy), 0.f);
        float ezf = fmaxf(fmaxf(bloz - czf, czf - bhiz), 0.f);
        float dmsqf = fmaf(exf, exf, fmaf(eyf, eyf, ezf * ezf));
        double tupper = __longlong_as_double(__double_as_longlong(tmax) | 0x1FFFULL);
        bool doupd = !((double)dmsqf * 0.99999 > tupper);
        if (__any(doupd)) {
            if (doupd) {
                double t0 = 0.0, t1 = 0.0;
#pragma unroll
                for (int j = 0; j < 8; j += 2) {
                    float4 v0 = u.s.spts[tid | (j << 10)];
                    float4 v1 = u.s.spts[tid | ((j + 1) << 10)];
                    double dx0 = (double)v0.x - cx, dy0 = (double)v0.y - cy, dz0 = (double)v0.z - cz;
                    double d0 = fma(dx0, dx0, fma(dy0, dy0, dz0 * dz0));
                    double nk0 = fmin(dk[j], packkey(d0, tid * 8 + j));
                    dk[j] = nk0; t0 = fmax(t0, nk0);
                    double dx1 = (double)v1.x - cx, dy1 = (double)v1.y - cy, dz1 = (double)v1.z - cz;
                    double d1 = fma(dx1, dx1, fma(dy1, dy1, dz1 * dz1));
                    double nk1 = fmin(dk[j + 1], packkey(d1, tid * 8 + j + 1));
                    dk[j + 1] = nk1; t1 = fmax(t1, nk1);
                }
                tmax = fmax(t0, t1);
            }
            double v = tmax;
            v = dpp_fmax64<0x121, 0xF>(v);
            v = dpp_fmax64<0x122, 0xF>(v);
            v = dpp_fmax64<0x124, 0xF>(v);
            v = dpp_fmax64<0x128, 0xF>(v);
            v = dpp_fmax64<0x142, 0xa>(v);
            v = dpp_fmax64<0x143, 0x8>(v);
            int wlo = __builtin_amdgcn_readlane(__double2loint(v), 63);
            int whi = __builtin_amdgcn_readlane(__double2hiint(v), 63);
            wm = __hiloint2double(whi, wlo);
        }
        if (lane == 0) u.s.swd[t & 1][w] = wm;
        __syncthreads();
        double gv = u.s.swd[t & 1][lane & 15];
        gv = dpp_fmax64<0x121, 0xF>(gv);
        gv = dpp_fmax64<0x122, 0xF>(gv);
        gv = dpp_fmax64<0x124, 0xF>(gv);
        gv = dpp_fmax64<0x128, 0xF>(gv);
        int sp = (int)((unsigned int)__double_as_longlong(gv) & 0x1FFFu);
        float4 cw = u.s.spts[(sp >> 3) | ((sp & 7) << 10)];  // same addr: broadcast
        cxf = cw.x; cyf = cw.y; czf = cw.z;
        cx = (double)cxf; cy = (double)cyf; cz = (double)czf;
        if (tid == 0) fidx[b * NS + t] = __float_as_int(cw.w);
    }
}

// ---------------- brute-force kNN top-16: f32 prefilter, f64-exact inserts ----------------
// Skip rule: true insert means d64 < kd15. |d32-d64| <= 2.4e-7 rel, kd15f is a
// rounded-up f32 of kd15 times (1+1e-5) -> every true insert satisfies
// d32 <= kd15f. Selection provably identical to the all-f64 version.
#define KT2 1024
__global__ void __launch_bounds__(256) k_knn(const float* __restrict__ xin, const int* __restrict__ fidx,
                                             int* __restrict__ knn) {
    __shared__ float sxf[KT2], syf[KT2], szf[KT2];      // 12 KB
    __shared__ double mk[4][16][64];                     // 32 KB: [part][rank][query]
    int tid = threadIdx.x;
    int part = tid >> 6;
    int ql = tid & 63;
    int gq = blockIdx.x * 64 + ql;
    int b = gq >> 12;
    const float* xb = xin + (size_t)b * NPTS * 3;
    int qi = fidx[gq];
    float qxf = xb[qi * 3], qyf = xb[qi * 3 + 1], qzf = xb[qi * 3 + 2];
    double qx = (double)qxf, qy = (double)qyf, qz = (double)qzf;
    double kd0 = DBL_MAX, kd1 = DBL_MAX, kd2 = DBL_MAX, kd3 = DBL_MAX,
           kd4 = DBL_MAX, kd5 = DBL_MAX, kd6 = DBL_MAX, kd7 = DBL_MAX,
           kd8 = DBL_MAX, kd9 = DBL_MAX, kd10 = DBL_MAX, kd11 = DBL_MAX,
           kd12 = DBL_MAX, kd13 = DBL_MAX, kd14 = DBL_MAX, kd15 = DBL_MAX;
    float kd15f = FLT_MAX;
    for (int tile = 0; tile < NPTS / KT2; tile++) {
        for (int m = tid; m < KT2; m += 256) {
            int gj = tile * KT2 + m;
            sxf[m] = xb[gj * 3]; syf[m] = xb[gj * 3 + 1]; szf[m] = xb[gj * 3 + 2];
        }
        __syncthreads();
        int base = part * (KT2 / 4);
        for (int m = 0; m < KT2 / 4; m++) {
            int li = base + m;
            float fdx = qxf - sxf[li], fdy = qyf - syf[li], fdz = qzf - szf[li];
            float d32 = fmaf(fdx, fdx, fmaf(fdy, fdy, fdz * fdz));
            if (d32 <= kd15f) {
                double dx = qx - (double)sxf[li], dy = qy - (double)syf[li], dz = qz - (double)szf[li];
                double d = fma(dx, dx, fma(dy, dy, dz * dz));
                double key = __longlong_as_double(
                    (__double_as_longlong(d) & 0xFFFFFFFFFFFFE000ULL)
                    | (unsigned long long)(tile * KT2 + li));
                if (key < kd15) {
                    kd15 = fmax(kd14, fmin(kd15, key)); kd14 = fmax(kd13, fmin(kd14, key));
                    kd13 = fmax(kd12, fmin(kd13, key)); kd12 = fmax(kd11, fmin(kd12, key));
                    kd11 = fmax(kd10, fmin(kd11, key)); kd10 = fmax(kd9,  fmin(kd10, key));
                    kd9  = fmax(kd8,  fmin(kd9,  key)); kd8  = fmax(kd7,  fmin(kd8,  key));
                    kd7  = fmax(kd6,  fmin(kd7,  key)); kd6  = fmax(kd5,  fmin(kd6,  key));
                    kd5  = fmax(kd4,  fmin(kd5,  key)); kd4  = fmax(kd3,  fmin(kd4,  key));
                    kd3  = fmax(kd2,  fmin(kd3,  key)); kd2  = fmax(kd1,  fmin(kd2,  key));
                    kd1  = fmax(kd0,  fmin(kd1,  key)); kd0  = fmin(kd0,  key);
                    kd15f = (kd15 >= DBL_MAX) ? FLT_MAX
                          : __double2float_ru(kd15) * (1.0f + 1e-5f);
                }
            }
        }
        __syncthreads();
    }
    mk[part][0][ql] = kd0;  mk[part][1][ql] = kd1;  mk[part][2][ql] = kd2;  mk[part][3][ql] = kd3;
    mk[part][4][ql] = kd4;  mk[part][5][ql] = kd5;  mk[part][6][ql] = kd6;  mk[part][7][ql] = kd7;
    mk[part][8][ql] = kd8;  mk[part][9][ql] = kd9;  mk[part][10][ql] = kd10; mk[part][11][ql] = kd11;
    mk[part][12][ql] = kd12; mk[part][13][ql] = kd13; mk[part][14][ql] = kd14; mk[part][15][ql] = kd15;
    __syncthreads();
    if (tid < 64) {
        int i0 = 0, i1 = 0, i2 = 0, i3 = 0;
        double h0 = mk[0][0][tid], h1 = mk[1][0][tid], h2 = mk[2][0][tid], h3 = mk[3][0][tid];
        int* outp = knn + (size_t)(blockIdx.x * 64 + tid) * 16;
#pragma unroll
        for (int k = 0; k < 16; k++) {
            double mm = fmin(fmin(h0, h1), fmin(h2, h3));
            outp[k] = (int)(__double_as_longlong(mm) & 0x1FFFULL);
            if (mm == h0)      { i0++; h0 = (i0 < 16) ? mk[0][i0][tid] : DBL_MAX; }
            else if (mm == h1) { i1++; h1 = (i1 < 16) ? mk[1][i1][tid] : DBL_MAX; }
            else if (mm == h2) { i2++; h2 = (i2 < 16) ? mk[2][i2][tid] : DBL_MAX; }
            else               { i3++; h3 = (i3 < 16) ? mk[3][i3][tid] : DBL_MAX; }
        }
    }
}

// ---------------- gather + maxpool(67) + conv3 (wave per point, no per-iter barriers) ----------------
__global__ void __launch_bounds__(256) k_group(const float* __restrict__ xin, const float* __restrict__ feat,
                                               const int* __restrict__ fidx, const int* __restrict__ knn,
                                               const float* __restrict__ W3, const float* __restrict__ b3,
                                               float* __restrict__ y3, float* __restrict__ stats) {
    __shared__ float W3s[OUTC * CATC];
    __shared__ float x67[4][68];
    __shared__ float lsum[64], lsq[64];
    int tid = threadIdx.x, w = tid >> 6, lane = tid & 63;
    for (int i = tid; i < OUTC * CATC; i += 256) W3s[i] = W3[i];
    if (tid < 64) { lsum[tid] = 0.f; lsq[tid] = 0.f; }
    __syncthreads();
    float bb3 = b3[lane];
    float psum = 0.f, psq = 0.f;
    int p0 = blockIdx.x * 64 + w * 16;
    for (int it = 0; it < 16; it++) {
        int p = p0 + it;
        int b = p >> 12;
        int myidx = knn[p * 16 + (lane & 15)];
        int nbk[16];
#pragma unroll
        for (int k = 0; k < 16; k++) nbk[k] = __shfl(myidx, k);
        float m = -FLT_MAX;
#pragma unroll
        for (int k = 0; k < 16; k++) m = fmaxf(m, feat[(size_t)(b * NPTS + nbk[k]) * OUTC + lane]);
        x67[w][3 + lane] = m;
        if (lane < 3) {
            int ci = fidx[p];
            float cc = xin[(size_t)(b * NPTS + ci) * 3 + lane];
            float mg = -FLT_MAX;
#pragma unroll
            for (int k = 0; k < 16; k++) mg = fmaxf(mg, xin[(size_t)(b * NPTS + nbk[k]) * 3 + lane] - cc);
            x67[w][lane] = mg;
        }
        float acc = bb3;
#pragma unroll
        for (int c = 0; c < CATC; c++) acc = fmaf(W3s[lane * CATC + c], x67[w][c], acc);
        y3[(size_t)p * OUTC + lane] = acc;
        psum += acc; psq = fmaf(acc, acc, psq);
    }
    atomicAdd(&lsum[lane], psum);
    atomicAdd(&lsq[lane], psq);
    __syncthreads();
    if (tid < 64) { atomicAdd(&stats[64 + tid], lsum[tid]); atomicAdd(&stats[128 + tid], lsq[tid]); }
}

// ---------------- BN2 finalize ----------------
__global__ void k_stats2(float* __restrict__ stats) {
    int c = threadIdx.x;  // 64
    float m = stats[64 + c] / (float)TOTAL_S;
    float var = stats[128 + c] / (float)TOTAL_S - m * m;
    stats[192 + c] = m;
    stats[256 + c] = rsqrtf(var + BN_EPS);
}

// ---------------- final conv with fused BN2+ReLU ----------------
__global__ void __launch_bounds__(256) k_last(const float* __restrict__ y3, const float* __restrict__ stats,
                                              const float* __restrict__ g2, const float* __restrict__ be2,
                                              const float* __restrict__ W4, const float* __restrict__ b4,
                                              float* __restrict__ out) {
    __shared__ float W4t[OUTC * OUTC];
    __shared__ float xs[4][64];
    int tid = threadIdx.x;
    for (int i = tid; i < OUTC * OUTC; i += 256) W4t[(i & 63) * 64 + (i >> 6)] = W4[i];
    int lp = tid >> 6, o = tid & 63;
    int p = blockIdx.x * 4 + lp;
    float v = y3[(size_t)p * OUTC + o];
    v = fmaf((v - stats[192 + o]) * stats[256 + o], g2[o], be2[o]);
    xs[lp][o] = fmaxf(v, 0.f);
    __syncthreads();
    const float* xp = xs[lp];
    float acc = b4[o];
#pragma unroll
    for (int c = 0; c < OUTC; c++) acc = fmaf(W4t[c * 64 + o], xp[c], acc);
    out[(size_t)p * OUTC + o] = acc;
}

extern "C" void kernel_launch(void* const* d_in, const int* in_sizes, int n_in,
                              void* d_out, int out_size, void* d_ws, size_t ws_size,
                              hipStream_t stream) {
    const float* xin = (const float*)d_in[0];
    const float* W1  = (const float*)d_in[1];
    const float* b1  = (const float*)d_in[2];
    const float* g1  = (const float*)d_in[3];
    const float* be1 = (const float*)d_in[4];
    const float* W2  = (const float*)d_in[5];
    const float* b2  = (const float*)d_in[6];
    const float* W3  = (const float*)d_in[7];
    const float* b3  = (const float*)d_in[8];
    const float* g2  = (const float*)d_in[9];
    const float* be2 = (const float*)d_in[10];
    const float* W4  = (const float*)d_in[11];
    const float* b4  = (const float*)d_in[12];
    float* out = (float*)d_out;

    float* ws = (float*)d_ws;
    float* feat = ws;                                       // 32768*64 = 2,097,152 f
    int*   fidx = (int*)(feat + (size_t)TOTAL_PTS * OUTC);  // 16384 i
    int*   knn  = fidx + TOTAL_S;                           // 262,144 i
    float* y3   = (float*)(knn + (size_t)TOTAL_S * 16);     // 1,048,576 f
    float* stats = y3 + (size_t)TOTAL_S * OUTC;             // 320 f
    double* mom = (double*)(stats + 320);                   // 9 d (8-aligned: all prior counts even)

    k_init<<<1, 256, 0, stream>>>(stats, mom);
    k_mom<<<32, 256, 0, stream>>>(xin, mom);
    k_bn1stats<<<1, 32, 0, stream>>>(mom, W1, b1, stats);
    k_featx<<<TOTAL_PTS / 256, 256, 0, stream>>>(xin, stats, W1, b1, g1, be1, W2, b2, feat);
    k_fps<<<NB, 1024, 0, stream>>>(xin, fidx);
    k_knn<<<TOTAL_S / 64, 256, 0, stream>>>(xin, fidx, knn);
    k_group<<<TOTAL_S / 64, 256, 0, stream>>>(xin, feat, fidx, knn, W3, b3, y3, stats);
    k_stats2<<<1, 64, 0, stream>>>(stats);
    k_last<<<TOTAL_S / 4, 256, 0, stream>>>(y3, stats, g2, be2, W4, b4, out);
}

// Round 14
// 4233.189 us; speedup vs baseline: 1.0417x; 1.0397x over previous
//
#include <hip/hip_runtime.h>
#include <float.h>
#include <math.h>

#define NB 4
#define NPTS 8192
#define NS 4096
#define MIDC 32
#define OUTC 64
#define CATC 67
#define BN_EPS 1e-5f
#define TOTAL_PTS (NB*NPTS)   // 32768
#define TOTAL_S (NB*NS)       // 16384
#define KT2 1024
#define N_FEATX_ITEMS 128
#define N_KNN_ITEMS 256
#define N_WORKERS 128

// Packed selection key: for non-negative doubles the IEEE754 bit pattern is
// order-isomorphic to the value. Truncate the low 13 mantissa bits and store a
// 13-bit id: (dist,id) compare = one f64 compare; min-update = one fmin.
__device__ __forceinline__ double packkey(double d, int sp) {
    return __longlong_as_double((__double_as_longlong(d) & 0xFFFFFFFFFFFFE000ULL)
                                | (unsigned long long)sp);
}

template<int CTRL, int RM>
__device__ __forceinline__ double dpp_fmax64(double v) {
    int lo = __builtin_amdgcn_update_dpp(0, __double2loint(v), CTRL, RM, 0xF, false);
    int hi = __builtin_amdgcn_update_dpp(0, __double2hiint(v), CTRL, RM, 0xF, false);
    return fmax(v, __hiloint2double(hi, lo));
}

__device__ __forceinline__ unsigned int mpart(unsigned int x) {
    x &= 1023u;
    x = (x | (x << 16)) & 0x030000FFu;
    x = (x | (x << 8))  & 0x0300F00Fu;
    x = (x | (x << 4))  & 0x030C30C3u;
    x = (x | (x << 2))  & 0x09249249u;
    return x;
}

// ---------------- init: zero accumulators, moments, counters ----------------
__global__ void k_init(float* __restrict__ stats, double* __restrict__ mom, int* __restrict__ ctrs) {
    int tid = threadIdx.x;
    if (tid < 128) stats[64 + tid] = 0.f;
    if (tid < 9) mom[tid] = 0.0;
    if (tid < 2) ctrs[tid] = 0;
}

// ---------------- xin moments: E[x], E[x x^T] (f64) ----------------
__global__ void __launch_bounds__(256) k_mom(const float* __restrict__ xin, double* __restrict__ mom) {
    int t = blockIdx.x * 256 + threadIdx.x;
    double sx = 0, sy = 0, sz = 0, sxx = 0, sxy = 0, sxz = 0, syy = 0, syz = 0, szz = 0;
#pragma unroll
    for (int j = 0; j < 4; j++) {
        int p = t * 4 + j;
        double x = (double)xin[p * 3], y = (double)xin[p * 3 + 1], z = (double)xin[p * 3 + 2];
        sx += x; sy += y; sz += z;
        sxx = fma(x, x, sxx); sxy = fma(x, y, sxy); sxz = fma(x, z, sxz);
        syy = fma(y, y, syy); syz = fma(y, z, syz); szz = fma(z, z, szz);
    }
#pragma unroll
    for (int off = 32; off; off >>= 1) {
        sx += __shfl_down(sx, off); sy += __shfl_down(sy, off); sz += __shfl_down(sz, off);
        sxx += __shfl_down(sxx, off); sxy += __shfl_down(sxy, off); sxz += __shfl_down(sxz, off);
        syy += __shfl_down(syy, off); syz += __shfl_down(syz, off); szz += __shfl_down(szz, off);
    }
    if ((threadIdx.x & 63) == 0) {
        atomicAdd(&mom[0], sx); atomicAdd(&mom[1], sy); atomicAdd(&mom[2], sz);
        atomicAdd(&mom[3], sxx); atomicAdd(&mom[4], sxy); atomicAdd(&mom[5], sxz);
        atomicAdd(&mom[6], syy); atomicAdd(&mom[7], syz); atomicAdd(&mom[8], szz);
    }
}

// ---------------- BN1 stats analytically ----------------
__global__ void k_bn1stats(const double* __restrict__ mom, const float* __restrict__ W1,
                           const float* __restrict__ b1, float* __restrict__ stats) {
    int c = threadIdx.x;  // 32
    double n = (double)TOTAL_PTS;
    double mx = mom[0] / n, my = mom[1] / n, mz = mom[2] / n;
    double Cxx = mom[3] / n - mx * mx, Cxy = mom[4] / n - mx * my, Cxz = mom[5] / n - mx * mz;
    double Cyy = mom[6] / n - my * my, Cyz = mom[7] / n - my * mz, Czz = mom[8] / n - mz * mz;
    double wx = (double)W1[c * 3], wy = (double)W1[c * 3 + 1], wz = (double)W1[c * 3 + 2];
    double mu = wx * mx + wy * my + wz * mz + (double)b1[c];
    double var = wx * wx * Cxx + wy * wy * Cyy + wz * wz * Czz
               + 2.0 * (wx * wy * Cxy + wx * wz * Cxz + wy * wz * Cyz);
    stats[c] = (float)mu;
    stats[32 + c] = rsqrtf(fmaxf((float)var, 0.f) + BN_EPS);
}

// =================== MEGA kernel: fps producer + worker consumers ===================
// Blocks 0..3: FPS (1 batch each, 1024 thr, r11-proven body; fidx stores are
// agent-scope so workers on other XCDs see them).
// Blocks 4..131: workers (256 thr; waves 4-15 exit). Work items via atomic
// counter: items 0..127 = featx tiles; 128..383 = knn+group tiles (64 queries).
// knn spins per-query on fidx (poison 0xAA > 8191 = sentinel); group spins on
// featx-done==128 (acquire) before reading feat.
// Deadlock-free: 132 blocks x 1 block/CU (129KB LDS) <= 256 CUs -> all
// co-resident; fps depends on nothing.
union MU {
    struct { float4 spts[NPTS]; double swd[2][16]; float bbx[16][6]; } f;          // fps 131712 B
    struct { float sxf[KT2], syf[KT2], szf[KT2]; double mk[4][16][64]; } k;        // knn 45056 B
    struct { float W2s[OUTC * MIDC]; float w1s[MIDC * 3], b1s[MIDC], p1[MIDC], p2[MIDC]; } x;
    struct { float W3s[OUTC * CATC]; float x67[4][68]; float lsum[64], lsq[64]; } g;
};

__device__ void do_fps(MU& u, const float* __restrict__ xin, int* __restrict__ fidx) {
    const int b = blockIdx.x;
    const int tid = threadIdx.x;
    const int lane = tid & 63, w = tid >> 6;  // 16 waves
    const float* xb = xin + (size_t)b * NPTS * 3;

    // ---- phase 0: batch bbox ----
    float mnx = FLT_MAX, mny = FLT_MAX, mnz = FLT_MAX;
    float mxx = -FLT_MAX, mxy = -FLT_MAX, mxz = -FLT_MAX;
    for (int j = 0; j < 8; j++) {
        int p = tid + (j << 10);
        float x = xb[p * 3], y = xb[p * 3 + 1], z = xb[p * 3 + 2];
        mnx = fminf(mnx, x); mny = fminf(mny, y); mnz = fminf(mnz, z);
        mxx = fmaxf(mxx, x); mxy = fmaxf(mxy, y); mxz = fmaxf(mxz, z);
    }
#pragma unroll
    for (int off = 32; off; off >>= 1) {
        mnx = fminf(mnx, __shfl_xor(mnx, off)); mny = fminf(mny, __shfl_xor(mny, off));
        mnz = fminf(mnz, __shfl_xor(mnz, off));
        mxx = fmaxf(mxx, __shfl_xor(mxx, off)); mxy = fmaxf(mxy, __shfl_xor(mxy, off));
        mxz = fmaxf(mxz, __shfl_xor(mxz, off));
    }
    if (lane == 0) {
        u.f.bbx[w][0] = mnx; u.f.bbx[w][1] = mny; u.f.bbx[w][2] = mnz;
        u.f.bbx[w][3] = mxx; u.f.bbx[w][4] = mxy; u.f.bbx[w][5] = mxz;
    }
    __syncthreads();
#pragma unroll
    for (int i = 0; i < 16; i++) {
        mnx = fminf(mnx, u.f.bbx[i][0]); mny = fminf(mny, u.f.bbx[i][1]);
        mnz = fminf(mnz, u.f.bbx[i][2]);
        mxx = fmaxf(mxx, u.f.bbx[i][3]); mxy = fmaxf(mxy, u.f.bbx[i][4]);
        mxz = fmaxf(mxz, u.f.bbx[i][5]);
    }
    float scx = 1023.0f / fmaxf(mxx - mnx, 1e-20f);
    float scy = 1023.0f / fmaxf(mxy - mny, 1e-20f);
    float scz = 1023.0f / fmaxf(mxz - mnz, 1e-20f);
    __syncthreads();

    // ---- phase 1: Morton keys + bitonic sort (karr overlays spts) ----
    unsigned long long* karr = (unsigned long long*)&u;
    for (int j = 0; j < 8; j++) {
        int p = tid + (j << 10);
        float x = xb[p * 3], y = xb[p * 3 + 1], z = xb[p * 3 + 2];
        unsigned int ix = (unsigned int)min(1023, max(0, (int)((x - mnx) * scx)));
        unsigned int iy = (unsigned int)min(1023, max(0, (int)((y - mny) * scy)));
        unsigned int iz = (unsigned int)min(1023, max(0, (int)((z - mnz) * scz)));
        unsigned long long code = (unsigned long long)((mpart(ix) << 2) | (mpart(iy) << 1) | mpart(iz));
        karr[p] = (code << 13) | (unsigned long long)p;
    }
    __syncthreads();
    for (int k = 2; k <= NPTS; k <<= 1) {
        for (int jj = k >> 1; jj > 0; jj >>= 1) {
            for (int pos = tid; pos < NPTS; pos += 1024) {
                int l2 = pos ^ jj;
                if (l2 > pos) {
                    unsigned long long a = karr[pos], c = karr[l2];
                    bool up = ((pos & k) == 0);
                    if ((up && a > c) || (!up && a < c)) { karr[pos] = c; karr[l2] = a; }
                }
            }
            __syncthreads();
        }
    }

    // ---- phase 2: gather sorted points into swizzled LDS, per-thread box ----
    unsigned long long kk[8];
#pragma unroll
    for (int j = 0; j < 8; j++) kk[j] = karr[tid * 8 + j];
    __syncthreads();
    float blox = FLT_MAX, bloy = FLT_MAX, bloz = FLT_MAX;
    float bhix = -FLT_MAX, bhiy = -FLT_MAX, bhiz = -FLT_MAX;
    double dk[8];
#pragma unroll
    for (int j = 0; j < 8; j++) {
        int oi = (int)(kk[j] & 0x1FFFULL);
        float x = xb[oi * 3], y = xb[oi * 3 + 1], z = xb[oi * 3 + 2];
        int sp = tid * 8 + j;
        int slot = (sp >> 3) | ((sp & 7) << 10);
        u.f.spts[slot] = make_float4(x, y, z, __int_as_float(oi));
        blox = fminf(blox, x); bloy = fminf(bloy, y); bloz = fminf(bloz, z);
        bhix = fmaxf(bhix, x); bhiy = fmaxf(bhiy, y); bhiz = fmaxf(bhiz, z);
        dk[j] = packkey(1e10, sp);
    }
    if (tid == 0)
        __hip_atomic_store(&fidx[b * NS], 0, __ATOMIC_RELAXED, __HIP_MEMORY_SCOPE_AGENT);
    __syncthreads();

    // ---- phase 3: main loop ----
    float cxf = xb[0], cyf = xb[1], czf = xb[2];
    double cx = (double)cxf, cy = (double)cyf, cz = (double)czf;
    double tmax = packkey(1e10, tid * 8 + 7);
    double wm = 0.0;
    for (int t = 1; t < NS; t++) {
        float exf = fmaxf(fmaxf(blox - cxf, cxf - bhix), 0.f);
        float eyf = fmaxf(fmaxf(bloy - cyf, cyf - bhiy), 0.f);
        float ezf = fmaxf(fmaxf(bloz - czf, czf - bhiz), 0.f);
        float dmsqf = fmaf(exf, exf, fmaf(eyf, eyf, ezf * ezf));
        double tupper = __longlong_as_double(__double_as_longlong(tmax) | 0x1FFFULL);
        bool doupd = !((double)dmsqf * 0.99999 > tupper);
        if (__any(doupd)) {
            if (doupd) {
                double t0 = 0.0, t1 = 0.0;
#pragma unroll
                for (int j = 0; j < 8; j += 2) {
                    float4 v0 = u.f.spts[tid | (j << 10)];
                    float4 v1 = u.f.spts[tid | ((j + 1) << 10)];
                    double dx0 = (double)v0.x - cx, dy0 = (double)v0.y - cy, dz0 = (double)v0.z - cz;
                    double d0 = fma(dx0, dx0, fma(dy0, dy0, dz0 * dz0));
                    double nk0 = fmin(dk[j], packkey(d0, tid * 8 + j));
                    dk[j] = nk0; t0 = fmax(t0, nk0);
                    double dx1 = (double)v1.x - cx, dy1 = (double)v1.y - cy, dz1 = (double)v1.z - cz;
                    double d1 = fma(dx1, dx1, fma(dy1, dy1, dz1 * dz1));
                    double nk1 = fmin(dk[j + 1], packkey(d1, tid * 8 + j + 1));
                    dk[j + 1] = nk1; t1 = fmax(t1, nk1);
                }
                tmax = fmax(t0, t1);
            }
            double v = tmax;
            v = dpp_fmax64<0x121, 0xF>(v);
            v = dpp_fmax64<0x122, 0xF>(v);
            v = dpp_fmax64<0x124, 0xF>(v);
            v = dpp_fmax64<0x128, 0xF>(v);
            v = dpp_fmax64<0x142, 0xa>(v);
            v = dpp_fmax64<0x143, 0x8>(v);
            int wlo = __builtin_amdgcn_readlane(__double2loint(v), 63);
            int whi = __builtin_amdgcn_readlane(__double2hiint(v), 63);
            wm = __hiloint2double(whi, wlo);
        }
        if (lane == 0) u.f.swd[t & 1][w] = wm;
        __syncthreads();
        double gv = u.f.swd[t & 1][lane & 15];
        gv = dpp_fmax64<0x121, 0xF>(gv);
        gv = dpp_fmax64<0x122, 0xF>(gv);
        gv = dpp_fmax64<0x124, 0xF>(gv);
        gv = dpp_fmax64<0x128, 0xF>(gv);
        int sp = (int)((unsigned int)__double_as_longlong(gv) & 0x1FFFu);
        float4 cw = u.f.spts[(sp >> 3) | ((sp & 7) << 10)];
        cxf = cw.x; cyf = cw.y; czf = cw.z;
        cx = (double)cxf; cy = (double)cyf; cz = (double)czf;
        if (tid == 0)
            __hip_atomic_store(&fidx[b * NS + t], __float_as_int(cw.w),
                               __ATOMIC_RELAXED, __HIP_MEMORY_SCOPE_AGENT);
    }
}

__device__ void do_featx(MU& u, int item, const float* __restrict__ xin, const float* __restrict__ stats,
                         const float* __restrict__ W1, const float* __restrict__ b1,
                         const float* __restrict__ g1, const float* __restrict__ be1,
                         const float* __restrict__ W2, const float* __restrict__ b2,
                         float* __restrict__ feat, int* __restrict__ ctrs) {
    int tid = threadIdx.x;
    for (int i = tid; i < OUTC * MIDC; i += 256) u.x.W2s[i] = W2[i];
    if (tid < MIDC * 3) u.x.w1s[tid] = W1[tid];
    if (tid < MIDC) {
        u.x.b1s[tid] = b1[tid];
        u.x.p1[tid] = stats[32 + tid] * g1[tid];
        u.x.p2[tid] = be1[tid] - stats[tid] * stats[32 + tid] * g1[tid];
    }
    __syncthreads();
    int p = item * 256 + tid;
    float x = xin[p * 3], y = xin[p * 3 + 1], z = xin[p * 3 + 2];
    float h[MIDC];
#pragma unroll
    for (int c = 0; c < MIDC; c++) {
        float v = fmaf(u.x.w1s[c * 3 + 2], z, fmaf(u.x.w1s[c * 3 + 1], y, fmaf(u.x.w1s[c * 3], x, u.x.b1s[c])));
        h[c] = fmaxf(fmaf(v, u.x.p1[c], u.x.p2[c]), 0.f);
    }
#pragma unroll 4
    for (int o = 0; o < OUTC; o++) {
        float a = b2[o];
#pragma unroll
        for (int c = 0; c < MIDC; c++) a = fmaf(u.x.W2s[o * MIDC + c], h[c], a);
        feat[p * OUTC + o] = a;
    }
    __syncthreads();
    if (tid == 0)
        __hip_atomic_fetch_add(&ctrs[1], 1, __ATOMIC_RELEASE, __HIP_MEMORY_SCOPE_AGENT);
}

__device__ void do_knn_group(MU& u, int item, const float* __restrict__ xin,
                             const int* __restrict__ fidx, int* __restrict__ knn,
                             const float* __restrict__ feat,
                             const float* __restrict__ W3, const float* __restrict__ b3,
                             float* __restrict__ y3, float* __restrict__ stats,
                             int* __restrict__ ctrs) {
    int tid = threadIdx.x;
    int part = tid >> 6;
    int ql = tid & 63;
    int gq = item * 64 + ql;
    int b = gq >> 12;
    const float* xb = xin + (size_t)b * NPTS * 3;
    // spin until FPS has produced this sample's index (ws poison 0xAA > 8191)
    unsigned int qv;
    for (;;) {
        qv = (unsigned int)__hip_atomic_load(&fidx[gq], __ATOMIC_RELAXED, __HIP_MEMORY_SCOPE_AGENT);
        if (qv <= 8191u) break;
        __builtin_amdgcn_s_sleep(8);
    }
    int qi = (int)qv;
    float qxf = xb[qi * 3], qyf = xb[qi * 3 + 1], qzf = xb[qi * 3 + 2];
    double qx = (double)qxf, qy = (double)qyf, qz = (double)qzf;
    double kd0 = DBL_MAX, kd1 = DBL_MAX, kd2 = DBL_MAX, kd3 = DBL_MAX,
           kd4 = DBL_MAX, kd5 = DBL_MAX, kd6 = DBL_MAX, kd7 = DBL_MAX,
           kd8 = DBL_MAX, kd9 = DBL_MAX, kd10 = DBL_MAX, kd11 = DBL_MAX,
           kd12 = DBL_MAX, kd13 = DBL_MAX, kd14 = DBL_MAX, kd15 = DBL_MAX;
    float kd15f = FLT_MAX;
    for (int tile = 0; tile < NPTS / KT2; tile++) {
        for (int m = tid; m < KT2; m += 256) {
            int gj = tile * KT2 + m;
            u.k.sxf[m] = xb[gj * 3]; u.k.syf[m] = xb[gj * 3 + 1]; u.k.szf[m] = xb[gj * 3 + 2];
        }
        __syncthreads();
        int base = part * (KT2 / 4);
        for (int m = 0; m < KT2 / 4; m++) {
            int li = base + m;
            float fdx = qxf - u.k.sxf[li], fdy = qyf - u.k.syf[li], fdz = qzf - u.k.szf[li];
            float d32 = fmaf(fdx, fdx, fmaf(fdy, fdy, fdz * fdz));
            if (d32 <= kd15f) {
                double dx = qx - (double)u.k.sxf[li], dy = qy - (double)u.k.syf[li], dz = qz - (double)u.k.szf[li];
                double d = fma(dx, dx, fma(dy, dy, dz * dz));
                double key = __longlong_as_double(
                    (__double_as_longlong(d) & 0xFFFFFFFFFFFFE000ULL)
                    | (unsigned long long)(tile * KT2 + li));
                if (key < kd15) {
                    kd15 = fmax(kd14, fmin(kd15, key)); kd14 = fmax(kd13, fmin(kd14, key));
                    kd13 = fmax(kd12, fmin(kd13, key)); kd12 = fmax(kd11, fmin(kd12, key));
                    kd11 = fmax(kd10, fmin(kd11, key)); kd10 = fmax(kd9,  fmin(kd10, key));
                    kd9  = fmax(kd8,  fmin(kd9,  key)); kd8  = fmax(kd7,  fmin(kd8,  key));
                    kd7  = fmax(kd6,  fmin(kd7,  key)); kd6  = fmax(kd5,  fmin(kd6,  key));
                    kd5  = fmax(kd4,  fmin(kd5,  key)); kd4  = fmax(kd3,  fmin(kd4,  key));
                    kd3  = fmax(kd2,  fmin(kd3,  key)); kd2  = fmax(kd1,  fmin(kd2,  key));
                    kd1  = fmax(kd0,  fmin(kd1,  key)); kd0  = fmin(kd0,  key);
                    kd15f = (kd15 >= DBL_MAX) ? FLT_MAX
                          : __double2float_ru(kd15) * (1.0f + 1e-5f);
                }
            }
        }
        __syncthreads();
    }
    u.k.mk[part][0][ql] = kd0;  u.k.mk[part][1][ql] = kd1;  u.k.mk[part][2][ql] = kd2;  u.k.mk[part][3][ql] = kd3;
    u.k.mk[part][4][ql] = kd4;  u.k.mk[part][5][ql] = kd5;  u.k.mk[part][6][ql] = kd6;  u.k.mk[part][7][ql] = kd7;
    u.k.mk[part][8][ql] = kd8;  u.k.mk[part][9][ql] = kd9;  u.k.mk[part][10][ql] = kd10; u.k.mk[part][11][ql] = kd11;
    u.k.mk[part][12][ql] = kd12; u.k.mk[part][13][ql] = kd13; u.k.mk[part][14][ql] = kd14; u.k.mk[part][15][ql] = kd15;
    __syncthreads();
    if (tid < 64) {
        int i0 = 0, i1 = 0, i2 = 0, i3 = 0;
        double h0 = u.k.mk[0][0][tid], h1 = u.k.mk[1][0][tid], h2 = u.k.mk[2][0][tid], h3 = u.k.mk[3][0][tid];
        int* outp = knn + (size_t)(item * 64 + tid) * 16;
#pragma unroll
        for (int k = 0; k < 16; k++) {
            double mm = fmin(fmin(h0, h1), fmin(h2, h3));
            outp[k] = (int)(__double_as_longlong(mm) & 0x1FFFULL);
            if (mm == h0)      { i0++; h0 = (i0 < 16) ? u.k.mk[0][i0][tid] : DBL_MAX; }
            else if (mm == h1) { i1++; h1 = (i1 < 16) ? u.k.mk[1][i1][tid] : DBL_MAX; }
            else if (mm == h2) { i2++; h2 = (i2 < 16) ? u.k.mk[2][i2][tid] : DBL_MAX; }
            else               { i3++; h3 = (i3 < 16) ? u.k.mk[3][i3][tid] : DBL_MAX; }
        }
    }
    // wait for all featx items (feat fully written) before the gather
    if (tid == 0) {
        while (__hip_atomic_load(&ctrs[1], __ATOMIC_ACQUIRE, __HIP_MEMORY_SCOPE_AGENT) < N_FEATX_ITEMS)
            __builtin_amdgcn_s_sleep(8);
    }
    __syncthreads();   // knn stores drained + LDS handoff to group overlay

    // ---- group: gather + maxpool(67) + conv3 (wave per point) ----
    int w = tid >> 6, lane = tid & 63;
    for (int i = tid; i < OUTC * CATC; i += 256) u.g.W3s[i] = W3[i];
    if (tid < 64) { u.g.lsum[tid] = 0.f; u.g.lsq[tid] = 0.f; }
    __syncthreads();
    float bb3 = b3[lane];
    float psum = 0.f, psq = 0.f;
    int p0 = item * 64 + w * 16;
    for (int it = 0; it < 16; it++) {
        int p = p0 + it;
        int pb = p >> 12;
        int myidx = knn[p * 16 + (lane & 15)];
        int nbk[16];
#pragma unroll
        for (int k = 0; k < 16; k++) nbk[k] = __shfl(myidx, k);
        float m = -FLT_MAX;
#pragma unroll
        for (int k = 0; k < 16; k++) m = fmaxf(m, feat[(size_t)(pb * NPTS + nbk[k]) * OUTC + lane]);
        u.g.x67[w][3 + lane] = m;
        if (lane < 3) {
            int ci = __hip_atomic_load(&fidx[p], __ATOMIC_RELAXED, __HIP_MEMORY_SCOPE_AGENT);
            float cc = xin[(size_t)(pb * NPTS + ci) * 3 + lane];
            float mg = -FLT_MAX;
#pragma unroll
            for (int k = 0; k < 16; k++) mg = fmaxf(mg, xin[(size_t)(pb * NPTS + nbk[k]) * 3 + lane] - cc);
            u.g.x67[w][lane] = mg;
        }
        float acc = bb3;
#pragma unroll
        for (int c = 0; c < CATC; c++) acc = fmaf(u.g.W3s[lane * CATC + c], u.g.x67[w][c], acc);
        y3[(size_t)p * OUTC + lane] = acc;
        psum += acc; psq = fmaf(acc, acc, psq);
    }
    atomicAdd(&u.g.lsum[lane], psum);
    atomicAdd(&u.g.lsq[lane], psq);
    __syncthreads();
    if (tid < 64) { atomicAdd(&stats[64 + tid], u.g.lsum[tid]); atomicAdd(&stats[128 + tid], u.g.lsq[tid]); }
}

__global__ void __launch_bounds__(1024) k_mega(const float* __restrict__ xin,
                                               const float* __restrict__ W1, const float* __restrict__ b1,
                                               const float* __restrict__ g1, const float* __restrict__ be1,
                                               const float* __restrict__ W2, const float* __restrict__ b2,
                                               const float* __restrict__ W3, const float* __restrict__ b3,
                                               float* __restrict__ stats, float* __restrict__ feat,
                                               int* __restrict__ fidx, int* __restrict__ knn,
                                               float* __restrict__ y3, int* __restrict__ ctrs) {
    __shared__ MU u;
    __shared__ int s_item;
    if (blockIdx.x < NB) { do_fps(u, xin, fidx); return; }
    if (threadIdx.x >= 256) return;   // worker waves 4-15 exit before any barrier
    int tid = threadIdx.x;
    for (;;) {
        __syncthreads();
        if (tid == 0) s_item = atomicAdd(&ctrs[0], 1);
        __syncthreads();
        int item = s_item;
        if (item >= N_FEATX_ITEMS + N_KNN_ITEMS) return;
        if (item < N_FEATX_ITEMS)
            do_featx(u, item, xin, stats, W1, b1, g1, be1, W2, b2, feat, ctrs);
        else
            do_knn_group(u, item - N_FEATX_ITEMS, xin, fidx, knn, feat, W3, b3, y3, stats, ctrs);
    }
}

// ---------------- BN2 finalize ----------------
__global__ void k_stats2(float* __restrict__ stats) {
    int c = threadIdx.x;  // 64
    float m = stats[64 + c] / (float)TOTAL_S;
    float var = stats[128 + c] / (float)TOTAL_S - m * m;
    stats[192 + c] = m;
    stats[256 + c] = rsqrtf(var + BN_EPS);
}

// ---------------- final conv with fused BN2+ReLU ----------------
__global__ void __launch_bounds__(256) k_last(const float* __restrict__ y3, const float* __restrict__ stats,
                                              const float* __restrict__ g2, const float* __restrict__ be2,
                                              const float* __restrict__ W4, const float* __restrict__ b4,
                                              float* __restrict__ out) {
    __shared__ float W4t[OUTC * OUTC];
    __shared__ float xs[4][64];
    int tid = threadIdx.x;
    for (int i = tid; i < OUTC * OUTC; i += 256) W4t[(i & 63) * 64 + (i >> 6)] = W4[i];
    int lp = tid >> 6, o = tid & 63;
    int p = blockIdx.x * 4 + lp;
    float v = y3[(size_t)p * OUTC + o];
    v = fmaf((v - stats[192 + o]) * stats[256 + o], g2[o], be2[o]);
    xs[lp][o] = fmaxf(v, 0.f);
    __syncthreads();
    const float* xp = xs[lp];
    float acc = b4[o];
#pragma unroll
    for (int c = 0; c < OUTC; c++) acc = fmaf(W4t[c * 64 + o], xp[c], acc);
    out[(size_t)p * OUTC + o] = acc;
}

extern "C" void kernel_launch(void* const* d_in, const int* in_sizes, int n_in,
                              void* d_out, int out_size, void* d_ws, size_t ws_size,
                              hipStream_t stream) {
    const float* xin = (const float*)d_in[0];
    const float* W1  = (const float*)d_in[1];
    const float* b1  = (const float*)d_in[2];
    const float* g1  = (const float*)d_in[3];
    const float* be1 = (const float*)d_in[4];
    const float* W2  = (const float*)d_in[5];
    const float* b2  = (const float*)d_in[6];
    const float* W3  = (const float*)d_in[7];
    const float* b3  = (const float*)d_in[8];
    const float* g2  = (const float*)d_in[9];
    const float* be2 = (const float*)d_in[10];
    const float* W4  = (const float*)d_in[11];
    const float* b4  = (const float*)d_in[12];
    float* out = (float*)d_out;

    float* ws = (float*)d_ws;
    float* feat = ws;                                       // 32768*64 = 2,097,152 f
    int*   fidx = (int*)(feat + (size_t)TOTAL_PTS * OUTC);  // 16384 i
    int*   knn  = fidx + TOTAL_S;                           // 262,144 i
    float* y3   = (float*)(knn + (size_t)TOTAL_S * 16);     // 1,048,576 f
    float* stats = y3 + (size_t)TOTAL_S * OUTC;             // 320 f
    double* mom = (double*)(stats + 320);                   // 9 d
    int* ctrs = (int*)(mom + 9);                            // [0]=work counter, [1]=featx done

    k_init<<<1, 256, 0, stream>>>(stats, mom, ctrs);
    k_mom<<<32, 256, 0, stream>>>(xin, mom);
    k_bn1stats<<<1, 32, 0, stream>>>(mom, W1, b1, stats);
    k_mega<<<NB + N_WORKERS, 1024, 0, stream>>>(xin, W1, b1, g1, be1, W2, b2, W3, b3,
                                                stats, feat, fidx, knn, y3, ctrs);
    k_stats2<<<1, 64, 0, stream>>>(stats);
    k_last<<<TOTAL_S / 4, 256, 0, stream>>>(y3, stats, g2, be2, W4, b4, out);
}